// Round 6
// baseline (128.101 us; speedup 1.0000x reference)
//
#include <hip/hip_runtime.h>
#include <hip/hip_fp16.h>
#include <hip/hip_cooperative_groups.h>
#include <math.h>

namespace cg = cooperative_groups;

// sigAct: u0 = sigmoid(-(lam_b*conv(1-2x))/eps); 5 damped updates.
// conv = separable 17-tap Gaussian (sigma=2) in LDS, f32 accumulation.
// Round-6: ONE cooperative kernel (1536 blocks = 256 CU x 6), grid.sync
// between steps; xl=(x,lam) persists in REGISTERS (no global xl buffer).
// Fallback: round-5 6-kernel path if occupancy/ws/coop-launch gate fails.

#define TILE 64
#define RAD  8
#define IN_W 80
#define HW   512
#define NIMG 24
#define NPIX ((size_t)HW * HW * NIMG)

// 1D normalized Gaussian, sigma=2, 17 taps: exp(-(k-8)^2/8) / 5.0131684
__device__ __constant__ const float GWc[17] = {
    6.6916e-05f, 4.3635e-04f, 2.2159612e-03f, 8.7643070e-03f,
    2.6995958e-02f, 6.4759932e-02f, 1.2098751e-01f, 1.7603572e-01f,
    1.9947466e-01f,
    1.7603572e-01f, 1.2098751e-01f, 6.4759932e-02f, 2.6995958e-02f,
    8.7643070e-03f, 2.2159612e-03f, 4.3635e-04f, 6.6916e-05f
};

struct alignas(8)  H4 { __half2 a, b; };
struct alignas(16) H8 { __half2 a, b, c, d; };

// sigmoid(-z) = 1/(1+exp(z)); inf->0, -inf->1.
__device__ __forceinline__ float inv1pexp(float z) {
    return __builtin_amdgcn_rcpf(1.0f + __expf(z));
}

// ---- shared phase helpers (identical math to round-5) ----
__device__ __forceinline__ void stage0_half(const __half* ub, __half* sIn,
                                            int t, int row0, int col0) {
#pragma unroll
    for (int i = 0; i < 4; ++i) {
        int q = t + i * 256;
        if (q < 800) {                     // 800 x 16B chunks (8 halfs)
            int r  = q / 10;
            int c8 = (q - r * 10) * 8;
            int gr = row0 + r - RAD;
            int gc = col0 + c8 - RAD;      // mult of 8 -> chunk fully in/out
            H8 v;
            if (gr >= 0 && gr < HW && gc >= 0 && gc < HW) {
                v = *reinterpret_cast<const H8*>(&ub[(size_t)gr * HW + gc]);
                const __half2 one2 = __floats2half2_rn(1.f, 1.f);
                v.a = __hsub2(one2, __hadd2(v.a, v.a));
                v.b = __hsub2(one2, __hadd2(v.b, v.b));
                v.c = __hsub2(one2, __hadd2(v.c, v.c));
                v.d = __hsub2(one2, __hadd2(v.d, v.d));
            } else {
                v.a = __floats2half2_rn(0.f, 0.f);
                v.b = v.a; v.c = v.a; v.d = v.a;
            }
            *reinterpret_cast<H8*>(&sIn[r * IN_W + c8]) = v;
        }
    }
}

__device__ __forceinline__ void stage0_f32(const float* xb, __half* sIn,
                                           int t, int row0, int col0) {
#pragma unroll
    for (int i = 0; i < 7; ++i) {
        int q = t + i * 256;
        if (q < 1600) {                    // 1600 float4 chunks
            int r  = q / 20;
            int c4 = (q - r * 20) * 4;
            int gr = row0 + r - RAD;
            int gc = col0 + c4 - RAD;      // mult of 4 -> chunk fully in/out
            H4 o;
            if (gr >= 0 && gr < HW && gc >= 0 && gc < HW) {
                float4 v = *reinterpret_cast<const float4*>(&xb[(size_t)gr * HW + gc]);
                o.a = __floats2half2_rn(1.f - 2.f * v.x, 1.f - 2.f * v.y);
                o.b = __floats2half2_rn(1.f - 2.f * v.z, 1.f - 2.f * v.w);
            } else {
                o.a = __floats2half2_rn(0.f, 0.f); o.b = o.a;
            }
            *reinterpret_cast<H4*>(&sIn[r * IN_W + c4]) = o;
        }
    }
}

__device__ __forceinline__ void hpass(const __half* sIn, __half* sTmp, int t) {
#pragma unroll
    for (int i = 0; i < 5; ++i) {
        int gq = t + i * 256;              // 1280 groups: 80 rows x 16
        int r  = gq >> 4;
        int cp = (gq & 15) * 4;
        const __half* wp = &sIn[r * IN_W + cp];
        float w[20];
#pragma unroll
        for (int j = 0; j < 5; ++j) {      // 5 x ds_read_b64
            H4 h = *reinterpret_cast<const H4*>(wp + j * 4);
            float2 f0 = __half22float2(h.a);
            float2 f1 = __half22float2(h.b);
            w[j*4+0] = f0.x; w[j*4+1] = f0.y;
            w[j*4+2] = f1.x; w[j*4+3] = f1.y;
        }
        float a0 = 0.f, a1 = 0.f, a2 = 0.f, a3 = 0.f;
#pragma unroll
        for (int k = 0; k < 17; ++k) {
            float g = GWc[k];
            a0 += g * w[k];     a1 += g * w[k + 1];
            a2 += g * w[k + 2]; a3 += g * w[k + 3];
        }
        H4 o; o.a = __floats2half2_rn(a0, a1); o.b = __floats2half2_rn(a2, a3);
        *reinterpret_cast<H4*>(&sTmp[r * TILE + cp]) = o;
    }
}

// ================= cooperative mega-kernel =================
__global__ __launch_bounds__(256, 6) void sig_all(
    const float* __restrict__ xg, const float* __restrict__ cgl,
    __half* __restrict__ u0, __half* __restrict__ u1,
    float* __restrict__ outp)
{
    __shared__ __half sIn [IN_W * IN_W];   // 12.8 KB
    __shared__ __half sTmp[IN_W * TILE];   // 10.2 KB

    cg::grid_group grid = cg::this_grid();

    const int t    = threadIdx.x;
    const int b    = blockIdx.x;           // 0..1535
    const int img  = b >> 6;
    const int rem  = b & 63;
    const int row0 = (rem >> 3) << 6;
    const int col0 = (rem &  7) << 6;
    const size_t ibase = (size_t)img * HW * HW;

    const int cc = t & 63;
    const int rg = t >> 6;
    const size_t pbase = ibase + (size_t)(row0 + rg * 16) * HW + (col0 + cc);

    __half2 xl[16];                        // (x, lam) per owned pixel

    // ===== INIT step: f = 1-2x =====
    stage0_f32(xg + ibase, sIn, t, row0, col0);
    __syncthreads();
    hpass(sIn, sTmp, t);
    __syncthreads();
    {
        float win[32];
#pragma unroll
        for (int j = 0; j < 32; ++j)
            win[j] = __half2float(sTmp[(rg * 16 + j) * TILE + cc]);
#pragma unroll
        for (int m = 0; m < 16; ++m) {
            float acc = 0.f;
#pragma unroll
            for (int k = 0; k < 17; ++k) acc += GWc[k] * win[m + k];
            size_t gidx = pbase + (size_t)m * HW;
            // recover x from LDS tile (same half quantization as xl pack)
            float xv  = 0.5f * (1.f -
                __half2float(sIn[(rg * 16 + m + RAD) * IN_W + (cc + RAD)]));
            float lam = 100.f * inv1pexp(-10.f * cgl[gidx]);
            xl[m] = __floats2half2_rn(xv, lam);
            u0[gidx] = __float2half(inv1pexp(lam * acc * 0.1f));
        }
    }

    // ===== 5 damped updates =====
#pragma unroll 1
    for (int s = 0; s < 5; ++s) {
        grid.sync();                       // prev writes visible, LDS free
        const __half* cur = (s & 1) ? u1 : u0;
        __half*       nxt = (s & 1) ? u0 : u1;

        stage0_half(cur + ibase, sIn, t, row0, col0);
        __syncthreads();
        hpass(sIn, sTmp, t);
        __syncthreads();

        float win[32];
#pragma unroll
        for (int j = 0; j < 32; ++j)
            win[j] = __half2float(sTmp[(rg * 16 + j) * TILE + cc]);
#pragma unroll
        for (int m = 0; m < 16; ++m) {
            float acc = 0.f;
#pragma unroll
            for (int k = 0; k < 17; ++k) acc += GWc[k] * win[m + k];
            size_t gidx = pbase + (size_t)m * HW;
            float2 p = __half22float2(xl[m]);          // (x, lam)
            float uprev = 0.5f * (1.f -
                __half2float(sIn[(rg * 16 + m + RAD) * IN_W + (cc + RAD)]));
            float tt = (uprev - p.x) * 10.f + p.y * acc;
            float uu = inv1pexp(tt * 0.1f);
            float res = 0.5f * uprev + 0.5f * uu;
            if (s < 4) nxt[gidx] = __float2half(res);
            else       outp[gidx] = res;
        }
    }
}

// ================= round-5 fallback path =================
template<int MODE> // 0=INIT 1=MID 2=FINAL
__global__ __launch_bounds__(256, 6) void sig_step(
    const __half* __restrict__ uin,
    const float*  __restrict__ xg,
    const float*  __restrict__ cgl,
    __half2* xl,
    void* uout)
{
    __shared__ __half sIn [IN_W * IN_W];
    __shared__ __half sTmp[IN_W * TILE];

    const int t    = threadIdx.x;
    const int img  = blockIdx.z;
    const int row0 = blockIdx.y * TILE;
    const int col0 = blockIdx.x * TILE;
    const size_t ibase = (size_t)img * HW * HW;

    if constexpr (MODE == 0) stage0_f32(xg + ibase, sIn, t, row0, col0);
    else                     stage0_half(uin + ibase, sIn, t, row0, col0);
    __syncthreads();
    hpass(sIn, sTmp, t);
    __syncthreads();

    const int cc = t & 63;
    const int rg = t >> 6;
    const size_t pbase = ibase + (size_t)(row0 + rg * 16) * HW + (col0 + cc);

    __half2 xlp[16];
    if constexpr (MODE == 2) {     // preload: xl may alias uout (d_out)
#pragma unroll
        for (int m = 0; m < 16; ++m) xlp[m] = xl[pbase + (size_t)m * HW];
    }

    float win[32];
#pragma unroll
    for (int j = 0; j < 32; ++j)
        win[j] = __half2float(sTmp[(rg * 16 + j) * TILE + cc]);

#pragma unroll
    for (int m = 0; m < 16; ++m) {
        float acc = 0.f;
#pragma unroll
        for (int k = 0; k < 17; ++k) acc += GWc[k] * win[m + k];

        size_t gidx = pbase + (size_t)m * HW;
        if constexpr (MODE == 0) {
            float xv  = xg[gidx];
            float lam = 100.f * inv1pexp(-10.f * cgl[gidx]);
            float res = inv1pexp(lam * acc * 0.1f);
            xl[gidx] = __floats2half2_rn(xv, lam);
            ((__half*)uout)[gidx] = __float2half(res);
        } else {
            float xv, lam;
            if constexpr (MODE == 2) {
                float2 p = __half22float2(xlp[m]); xv = p.x; lam = p.y;
            } else {
                float2 p = __half22float2(xl[gidx]); xv = p.x; lam = p.y;
            }
            float uprev = 0.5f * (1.f -
                __half2float(sIn[(rg * 16 + m + RAD) * IN_W + (cc + RAD)]));
            float tt = (uprev - xv) * 10.f + lam * acc;
            float uu = inv1pexp(tt * 0.1f);
            float res = 0.5f * uprev + 0.5f * uu;
            if constexpr (MODE == 2) ((float*)uout)[gidx] = res;
            else                     ((__half*)uout)[gidx] = __float2half(res);
        }
    }
}

extern "C" void kernel_launch(void* const* d_in, const int* in_sizes, int n_in,
                              void* d_out, int out_size, void* d_ws, size_t ws_size,
                              hipStream_t stream) {
    const float* x = (const float*)d_in[0];
    const float* c = (const float*)d_in[1];
    float* out = (float*)d_out;

    __half* u0 = (__half*)d_ws;          // NPIX halfs = 12.6 MB
    __half* u1 = u0 + NPIX;              // 12.6 MB

    // --- gate: cooperative path needs 6 blocks/CU residency + ws for u0,u1 ---
    bool coop = (ws_size >= NPIX * 4);
    if (coop) {
        int maxb = 0;
        if (hipOccupancyMaxActiveBlocksPerMultiprocessor(&maxb, sig_all, 256, 0)
                != hipSuccess || maxb < 6)
            coop = false;
    }
    if (coop) {
        void* args[] = { (void*)&x, (void*)&c, (void*)&u0, (void*)&u1, (void*)&out };
        if (hipLaunchCooperativeKernel(sig_all, dim3(NIMG * 64), dim3(256),
                                       args, 0, stream) == hipSuccess)
            return;
    }

    // --- fallback: round-5 six-kernel path ---
    __half2* xl;
    if (ws_size >= NPIX * 8)             // u0+u1 (4B/px) + xl (4B/px)
        xl = (__half2*)((char*)d_ws + NPIX * 4);
    else
        xl = (__half2*)d_out;            // safe: FINAL preloads before storing

    dim3 grid(HW / TILE, HW / TILE, NIMG);
    dim3 block(256);
    sig_step<0><<<grid, block, 0, stream>>>(nullptr, x, c, xl, u0);
    sig_step<1><<<grid, block, 0, stream>>>(u0, x, c, xl, u1);
    sig_step<1><<<grid, block, 0, stream>>>(u1, x, c, xl, u0);
    sig_step<1><<<grid, block, 0, stream>>>(u0, x, c, xl, u1);
    sig_step<1><<<grid, block, 0, stream>>>(u1, x, c, xl, u0);
    sig_step<2><<<grid, block, 0, stream>>>(u0, x, c, xl, d_out);
}